// Round 10
// baseline (200.651 us; speedup 1.0000x reference)
//
#include <hip/hip_runtime.h>
#include <hip/hip_bf16.h>

#define BATCH 8
#define SEQ   2048
#define DIM   128
#define NROWS 16384                       // BATCH*SEQ
#define THETA_SPAN 22.62741699796952f     // 2*sqrt(128) = 1/c ; c^2 = 1/512

typedef __bf16    bf16x8   __attribute__((ext_vector_type(8)));
typedef float     floatx4  __attribute__((ext_vector_type(4)));
typedef _Float16  half2v   __attribute__((ext_vector_type(2)));

static __device__ __forceinline__ unsigned short f2bf(float v) {
    union { __hip_bfloat16 h; unsigned short u; } c;
    c.h = __float2bfloat16(v);
    return c.u;
}
static __device__ __forceinline__ float bf2f(unsigned short u) {
    union { unsigned int i; float f; } c;
    c.i = (unsigned int)u << 16;
    return c.f;
}
static __device__ __forceinline__ unsigned short f2h(float v) {
    union { _Float16 h; unsigned short u; } c;
    c.h = (_Float16)v;
    return c.u;
}

#if __has_builtin(__builtin_amdgcn_fdot2)
static __device__ __forceinline__ float fdot2acc(half2v a, half2v b, float c) {
    return __builtin_amdgcn_fdot2(a, b, c, false);
}
#else
static __device__ __forceinline__ float fdot2acc(half2v a, half2v b, float c) {
    return fmaf((float)a.y, (float)b.y, fmaf((float)a.x, (float)b.x, c));
}
#endif

// ---------------------------------------------------------------------------
// Merged Q/K projection (unchanged from round 8/9 — verified).
// grid (NROWS/64, 2): y=0 -> Q (hi/lo bf16 split), y=1 -> K (bf16).
// Layout emits k-chunks k = kthi*8 + j; valid for BOTH 32x32 (kthi=kt*2+hi)
// and 16x16 (kthi=kt*4+quad) fragment enumerations.
// ---------------------------------------------------------------------------
__global__ void __launch_bounds__(256)
proj_qk(const float* __restrict__ xq, const float* __restrict__ xn,
        const float* __restrict__ Wq, const float* __restrict__ bq,
        const float* __restrict__ Wk, const float* __restrict__ bk,
        unsigned short* __restrict__ Qhi, unsigned short* __restrict__ Qlo,
        unsigned short* __restrict__ Kb) {
    const int isK = blockIdx.y;
    const float* __restrict__ X    = isK ? xn : xq;
    const float* __restrict__ W    = isK ? Wk : Wq;
    const float* __restrict__ bias = isK ? bk : bq;

    __shared__ float wt[64][133];   // wt[e'][d]
    __shared__ float xs[64][68];    // xs[r][e']
    const int tid  = threadIdx.x;
    const int l    = tid & 15;
    const int kthi = tid >> 4;
    const int row0 = blockIdx.x * 64;

    float s[4][8];
#pragma unroll
    for (int rr = 0; rr < 4; ++rr)
#pragma unroll
        for (int j = 0; j < 8; ++j) s[rr][j] = 0.0f;

    for (int ph = 0; ph < 2; ++ph) {
        const int e0 = ph * 64;
#pragma unroll
        for (int i = 0; i < 8; ++i) {
            const int g  = tid + 256 * i;          // g < 2048
            const int d  = g >> 4;
            const int c4 = g & 15;
            float4 wv = *reinterpret_cast<const float4*>(
                W + (size_t)d * DIM + e0 + 4 * c4);
            wt[4*c4+0][d] = wv.x;  wt[4*c4+1][d] = wv.y;
            wt[4*c4+2][d] = wv.z;  wt[4*c4+3][d] = wv.w;
        }
#pragma unroll
        for (int i = 0; i < 4; ++i) {
            const int g  = tid + 256 * i;          // g < 1024
            const int r  = g >> 4;
            const int c4 = g & 15;
            float4 xv = *reinterpret_cast<const float4*>(
                X + (size_t)(row0 + r) * DIM + e0 + 4 * c4);
            *reinterpret_cast<float4*>(&xs[r][4 * c4]) = xv;
        }
        __syncthreads();
#pragma unroll 8
        for (int e = 0; e < 64; ++e) {
            float w8[8];
            *reinterpret_cast<float4*>(w8)     =
                *reinterpret_cast<const float4*>(&wt[e][kthi * 8]);
            *reinterpret_cast<float4*>(w8 + 4) =
                *reinterpret_cast<const float4*>(&wt[e][kthi * 8 + 4]);
#pragma unroll
            for (int rr = 0; rr < 4; ++rr) {
                const float xv = xs[l + 16 * rr][e];
#pragma unroll
                for (int j = 0; j < 8; ++j) s[rr][j] = fmaf(xv, w8[j], s[rr][j]);
            }
        }
        __syncthreads();
    }

    float b8[8];
    *reinterpret_cast<float4*>(b8)     = *reinterpret_cast<const float4*>(bias + kthi * 8);
    *reinterpret_cast<float4*>(b8 + 4) = *reinterpret_cast<const float4*>(bias + kthi * 8 + 4);

    if (!isK) {
#pragma unroll
        for (int rr = 0; rr < 4; ++rr) {
            const int row = row0 + l + 16 * rr;
            union { uint4 v; unsigned short u[8]; } ph_, pl_;
#pragma unroll
            for (int j = 0; j < 8; ++j) {
                const float v = s[rr][j] + b8[j];
                const unsigned short h = f2bf(v);
                ph_.u[j] = h;
                pl_.u[j] = f2bf(v - bf2f(h));
            }
            const size_t base = ((size_t)kthi * NROWS + row) * 8;
            *reinterpret_cast<uint4*>(Qhi + base) = ph_.v;
            *reinterpret_cast<uint4*>(Qlo + base) = pl_.v;
        }
    } else {
#pragma unroll
        for (int rr = 0; rr < 4; ++rr) {
            const int row = row0 + l + 16 * rr;
            const int b   = row >> 11;
            const int key = row & (SEQ - 1);
            union { uint4 v; unsigned short u[8]; } pk;
#pragma unroll
            for (int j = 0; j < 8; ++j) pk.u[j] = f2bf(s[rr][j] + b8[j]);
            const size_t base = (((size_t)(b * 16) + kthi) * SEQ + key) * 8;
            *reinterpret_cast<uint4*>(Kb + base) = pk.v;
        }
    }
}

// ---------------------------------------------------------------------------
// FUSED scores + entmax, v2: 16 rows x 2048 keys per block, 512 threads
// (8 waves), 64 KB LDS -> 2 blocks/CU so one block's MFMA phase overlaps the
// other's VALU phase (round-9's 128KB tile forced 1 block/CU = strict
// pipe alternation).
// Phase 1: wave wv owns keys [wv*256, +256); mfma_f32_16x16x32_bf16
// (A/B: m|n = lane&15, k = (lane>>4)*8+j; C/D: col=lane&15,
// row=(lane>>4)*4+reg — m89/m91 verified). Reg-quad = 4 consecutive rows ->
// rowgroup-packed f16 LDS tile SW[quad][2k+sp], stride 4098 dwords.
// Phase 2: wave wv -> rowgroup wv>>1, sub-pair wv&1; both sub-rows'
// bisections run interleaved (independent chains, 2x ILP on shfl latency).
// Numerics identical to round 9: f16 scores, 11 packed-f16 iterations,
// predicate sum max(s-th,0)^2 >= 512.
// ---------------------------------------------------------------------------
__global__ void __launch_bounds__(512, 4)
attn_fused(const __bf16* __restrict__ Qhi, const __bf16* __restrict__ Qlo,
           const __bf16* __restrict__ Kb, float* __restrict__ out) {
    __shared__ unsigned int SW[4 * 4098];   // 4 rowgroups x (2048 keys x 2 + pad)
    const int tid  = threadIdx.x;
    const int wv   = tid >> 6;              // 0..7
    const int lane = tid & 63;
    const int l4   = lane & 15;
    const int quad = lane >> 4;             // 0..3
    const int row0 = blockIdx.x * 16;
    const int b    = row0 >> 11;
    const int key0 = wv * 256;

    // ---------------- phase 1: MFMA scores -> LDS ----------------
    {
        floatx4 acc[16];
        const floatx4 zerov = {};
#pragma unroll
        for (int t = 0; t < 16; ++t) acc[t] = zerov;

        const size_t qbase = ((size_t)quad * NROWS + row0 + l4) * 8;
        const size_t kbase = (((size_t)(b * 16) + quad) * SEQ + key0 + l4) * 8;
        const size_t qstep = (size_t)4 * NROWS * 8;   // kt -> kt+1
        const size_t kstep = (size_t)4 * SEQ * 8;

#pragma unroll
        for (int kt = 0; kt < 4; ++kt) {
            const bf16x8 ah = *reinterpret_cast<const bf16x8*>(Qhi + qbase + kt * qstep);
            const bf16x8 al = *reinterpret_cast<const bf16x8*>(Qlo + qbase + kt * qstep);
            const __bf16* kc = Kb + kbase + kt * kstep;
#pragma unroll
            for (int t = 0; t < 16; ++t) {
                const bf16x8 bkv = *reinterpret_cast<const bf16x8*>(kc + (size_t)t * 128);
                acc[t] = __builtin_amdgcn_mfma_f32_16x16x32_bf16(ah, bkv, acc[t], 0, 0, 0);
                acc[t] = __builtin_amdgcn_mfma_f32_16x16x32_bf16(al, bkv, acc[t], 0, 0, 0);
            }
        }
        // C/D: col = l4 (key), row = quad*4 + reg -> reg-quad = rowgroup `quad`
#pragma unroll
        for (int t = 0; t < 16; ++t) {
            union { uint2 v; unsigned short u[4]; } pk;
#pragma unroll
            for (int bb = 0; bb < 4; ++bb) pk.u[bb] = f2h(acc[t][bb]);
            const int key = key0 + t * 16 + l4;
            *reinterpret_cast<uint2*>(&SW[quad * 4098 + 2 * key]) = pk.v;
        }
    }
    __syncthreads();

    // ---------------- phase 2: entmax, 2 rows per wave, interleaved ----------
    const int g  = wv >> 1;                 // rowgroup 0..3
    const int sp = wv & 1;                  // rows 4g+2sp+{0,1}

    const unsigned int* Sw = &SW[g * 4098];
    unsigned int raw[32];
#pragma unroll
    for (int c = 0; c < 32; ++c) raw[c] = Sw[2 * (c * 64 + lane) + sp];

    // split into the two sub-rows' f16x2 key-pair vectors
    half2v z0[16], z1[16];
#pragma unroll
    for (int i = 0; i < 16; ++i) {
        union { unsigned int u; half2v h; } c0, c1;
        c0.u = __builtin_amdgcn_perm(raw[2 * i + 1], raw[2 * i], 0x05040100u);
        c1.u = __builtin_amdgcn_perm(raw[2 * i + 1], raw[2 * i], 0x07060302u);
        z0[i] = c0.h;
        z1[i] = c1.h;
    }

    const half2v hzero = {(_Float16)0.0f, (_Float16)0.0f};

    // row maxes (two independent chains)
    float m0 = -1e30f, m1 = -1e30f;
#pragma unroll
    for (int i = 0; i < 16; ++i) {
        m0 = fmaxf(m0, fmaxf((float)z0[i].x, (float)z0[i].y));
        m1 = fmaxf(m1, fmaxf((float)z1[i].x, (float)z1[i].y));
    }
#pragma unroll
    for (int off = 32; off >= 1; off >>= 1) {
        m0 = fmaxf(m0, __shfl_xor(m0, off, 64));
        m1 = fmaxf(m1, __shfl_xor(m1, off, 64));
    }

    // interleaved bisections: sum max(s - th, 0)^2 = 512, th in [m-1/c, m]
    float lo0 = m0 - THETA_SPAN, hi0 = m0;
    float lo1 = m1 - THETA_SPAN, hi1 = m1;
    for (int it = 0; it < 11; ++it) {
        const float th0 = 0.5f * (lo0 + hi0);
        const float th1 = 0.5f * (lo1 + hi1);
        const _Float16 t0h = (_Float16)th0;
        const _Float16 t1h = (_Float16)th1;
        const half2v n0 = {(_Float16)-t0h, (_Float16)-t0h};
        const half2v n1 = {(_Float16)-t1h, (_Float16)-t1h};
        float f0 = 0.0f, f1 = 0.0f;
#pragma unroll
        for (int i = 0; i < 16; ++i) {
            half2v d0 = z0[i] + n0;
            half2v d1 = z1[i] + n1;
            d0 = __builtin_elementwise_max(d0, hzero);
            d1 = __builtin_elementwise_max(d1, hzero);
            f0 = fdot2acc(d0, d0, f0);
            f1 = fdot2acc(d1, d1, f1);
        }
#pragma unroll
        for (int off = 32; off >= 1; off >>= 1) {
            f0 += __shfl_xor(f0, off, 64);
            f1 += __shfl_xor(f1, off, 64);
        }
        if (f0 >= 512.0f) lo0 = th0; else hi0 = th0;
        if (f1 >= 512.0f) lo1 = th1; else hi1 = th1;
    }
    float th0 = 0.5f * (lo0 + hi0);
    float th1 = 0.5f * (lo1 + hi1);
    th0 = (float)((_Float16)th0);   // evaluate at the quantized theta
    th1 = (float)((_Float16)th1);

    // epilogue: p = max(s-th,0)^2 / 512, f32 coalesced stores
    float* o0 = out + (size_t)(row0 + 4 * g + 2 * sp + 0) * SEQ + lane;
    float* o1 = out + (size_t)(row0 + 4 * g + 2 * sp + 1) * SEQ + lane;
#pragma unroll
    for (int i = 0; i < 16; ++i) {
        const float a0 = fmaxf((float)z0[i].x - th0, 0.0f);
        const float a1 = fmaxf((float)z0[i].y - th0, 0.0f);
        const float b0 = fmaxf((float)z1[i].x - th1, 0.0f);
        const float b1 = fmaxf((float)z1[i].y - th1, 0.0f);
        o0[(size_t)(2 * i) * 64]     = a0 * a0 * (1.0f / 512.0f);
        o0[(size_t)(2 * i + 1) * 64] = a1 * a1 * (1.0f / 512.0f);
        o1[(size_t)(2 * i) * 64]     = b0 * b0 * (1.0f / 512.0f);
        o1[(size_t)(2 * i + 1) * 64] = b1 * b1 * (1.0f / 512.0f);
    }
}

// ---------------------------------------------------------------------------
extern "C" void kernel_launch(void* const* d_in, const int* in_sizes, int n_in,
                              void* d_out, int out_size, void* d_ws, size_t ws_size,
                              hipStream_t stream) {
    const float* x_c = (const float*)d_in[0];
    const float* x_n = (const float*)d_in[1];
    const float* Wq  = (const float*)d_in[2];
    const float* bq  = (const float*)d_in[3];
    const float* Wk  = (const float*)d_in[4];
    const float* bk  = (const float*)d_in[5];
    float* out = (float*)d_out;

    char* ws = (char*)d_ws;
    unsigned short* Qhi = (unsigned short*)ws;                        // 4 MB
    unsigned short* Qlo = (unsigned short*)(ws + ((size_t)4 << 20));  // 4 MB
    unsigned short* Kbl = (unsigned short*)(ws + ((size_t)8 << 20));  // 4 MB

    proj_qk<<<dim3(NROWS / 64, 2), 256, 0, stream>>>(
        x_c, x_n, Wq, bq, Wk, bk, Qhi, Qlo, Kbl);
    attn_fused<<<NROWS / 16, 512, 0, stream>>>(
        (const __bf16*)Qhi, (const __bf16*)Qlo, (const __bf16*)Kbl, out);
}

// Round 11
// 193.596 us; speedup vs baseline: 1.0364x; 1.0364x over previous
//
#include <hip/hip_runtime.h>
#include <hip/hip_bf16.h>

#define BATCH 8
#define SEQ   2048
#define DIM   128
#define NROWS 16384                       // BATCH*SEQ
#define THETA_SPAN 22.62741699796952f     // 2*sqrt(128) = 1/c ; c^2 = 1/512

typedef __bf16    bf16x8   __attribute__((ext_vector_type(8)));
typedef float     floatx4  __attribute__((ext_vector_type(4)));
typedef _Float16  half2v   __attribute__((ext_vector_type(2)));

static __device__ __forceinline__ unsigned short f2bf(float v) {
    union { __hip_bfloat16 h; unsigned short u; } c;
    c.h = __float2bfloat16(v);
    return c.u;
}
static __device__ __forceinline__ float bf2f(unsigned short u) {
    union { unsigned int i; float f; } c;
    c.i = (unsigned int)u << 16;
    return c.f;
}
static __device__ __forceinline__ unsigned short f2h(float v) {
    union { _Float16 h; unsigned short u; } c;
    c.h = (_Float16)v;
    return c.u;
}

#if __has_builtin(__builtin_amdgcn_fdot2)
static __device__ __forceinline__ float fdot2acc(half2v a, half2v b, float c) {
    return __builtin_amdgcn_fdot2(a, b, c, false);
}
#else
static __device__ __forceinline__ float fdot2acc(half2v a, half2v b, float c) {
    return fmaf((float)a.y, (float)b.y, fmaf((float)a.x, (float)b.x, c));
}
#endif

// ---------------------------------------------------------------------------
// MFMA-based Q/K projection (replaces round-10's LDS-bound VALU proj: 768
// scalar LDS instr/thread ~= 20us). grid (NROWS/64, 2): y=0 -> Q (hi/lo bf16
// split), y=1 -> K (bf16). 64 rows/block, 256 thr (4 waves, wave w owns rows
// w*16+l4). D = W x X^T via mfma_f32_16x16x32_bf16:
//   A = W[d][e] (m=d), B = X[row][e] (n=row); X split hi+lo (2 MFMAs) so only
//   W's bf16 rounding adds error (~4e-3 raw-score rms -> p-err ~5e-4).
// C/D (m89/m91): col=lane&15 -> row(=n), m = quad*4+reg -> 4 CONSECUTIVE d
// per reg-quad -> packed ushort4 epilogue into LDS planes, then the round-8
// verified coalesced uint4 global stores (layouts unchanged byte-for-byte).
// LDS: XH(8704) XL(8704) W(17408) ushorts = 68KB -> 2 blocks/CU. Epilogue
// overlays Q planes on XH/XL (each wave overwrites only its OWN X rows after
// its last read -> no barrier needed before the overlay; one barrier before
// the cross-wave readback).
// ---------------------------------------------------------------------------
__global__ void __launch_bounds__(256, 2)
proj_qk(const float* __restrict__ xq, const float* __restrict__ xn,
        const float* __restrict__ Wq, const float* __restrict__ bq,
        const float* __restrict__ Wk, const float* __restrict__ bk,
        unsigned short* __restrict__ Qhi, unsigned short* __restrict__ Qlo,
        unsigned short* __restrict__ Kb) {
    const int isK = blockIdx.y;
    const float* __restrict__ X    = isK ? xn : xq;
    const float* __restrict__ W    = isK ? Wk : Wq;
    const float* __restrict__ bias = isK ? bk : bq;

    __shared__ __align__(16) unsigned short SM[34816];
    unsigned short* XH = SM;            // 64 x 136
    unsigned short* XL = SM + 8704;     // 64 x 136
    unsigned short* WW = SM + 17408;    // 128 x 136

    const int tid  = threadIdx.x;
    const int lane = tid & 63;
    const int wv   = tid >> 6;          // 0..3
    const int l4   = lane & 15;
    const int quad = lane >> 4;         // 0..3
    const int row0 = blockIdx.x * 64;

    // ---- stage X (64x128 f32 -> bf16 hi+lo), coalesced float4 reads ----
#pragma unroll
    for (int i = 0; i < 8; ++i) {
        const int g  = tid + 256 * i;          // g < 2048
        const int r  = g >> 5;
        const int c4 = g & 31;
        const float4 xv = *reinterpret_cast<const float4*>(
            X + (size_t)(row0 + r) * DIM + 4 * c4);
        union { ushort2 v[2]; unsigned short u[4]; } hh, ll;
        const float xf[4] = {xv.x, xv.y, xv.z, xv.w};
#pragma unroll
        for (int j = 0; j < 4; ++j) {
            const unsigned short h = f2bf(xf[j]);
            hh.u[j] = h;
            ll.u[j] = f2bf(xf[j] - bf2f(h));
        }
        *reinterpret_cast<uint2*>(&XH[r * 136 + 4 * c4]) =
            *reinterpret_cast<uint2*>(hh.u);
        *reinterpret_cast<uint2*>(&XL[r * 136 + 4 * c4]) =
            *reinterpret_cast<uint2*>(ll.u);
    }
    // ---- stage W (128x128 f32 -> bf16), coalesced ----
#pragma unroll
    for (int i = 0; i < 16; ++i) {
        const int g  = tid + 256 * i;          // g < 4096
        const int d  = g >> 5;
        const int c4 = g & 31;
        const float4 wvv = *reinterpret_cast<const float4*>(
            W + (size_t)d * DIM + 4 * c4);
        union { uint2 v; unsigned short u[4]; } pw;
        pw.u[0] = f2bf(wvv.x); pw.u[1] = f2bf(wvv.y);
        pw.u[2] = f2bf(wvv.z); pw.u[3] = f2bf(wvv.w);
        *reinterpret_cast<uint2*>(&WW[d * 136 + 4 * c4]) = pw.v;
    }
    __syncthreads();

    // ---- MFMA: acc[mt][reg] = Q/K value of (row = w*16+l4, d = mt*16+quad*4+reg)
    floatx4 acc[8];
    const floatx4 zerov = {};
#pragma unroll
    for (int mt = 0; mt < 8; ++mt) acc[mt] = zerov;

#pragma unroll
    for (int kt = 0; kt < 4; ++kt) {
        const int koff = kt * 32 + quad * 8;
        const bf16x8 xh = *reinterpret_cast<const bf16x8*>(
            &XH[(wv * 16 + l4) * 136 + koff]);
        const bf16x8 xl = *reinterpret_cast<const bf16x8*>(
            &XL[(wv * 16 + l4) * 136 + koff]);
#pragma unroll
        for (int mt = 0; mt < 8; ++mt) {
            const bf16x8 wf = *reinterpret_cast<const bf16x8*>(
                &WW[(mt * 16 + l4) * 136 + koff]);
            acc[mt] = __builtin_amdgcn_mfma_f32_16x16x32_bf16(wf, xh, acc[mt], 0, 0, 0);
            acc[mt] = __builtin_amdgcn_mfma_f32_16x16x32_bf16(wf, xl, acc[mt], 0, 0, 0);
        }
    }

    // ---- epilogue: +bias, convert, pack ushort4 into planes (own rows only)
    const int erow = wv * 16 + l4;      // this lane's output row
#pragma unroll
    for (int mt = 0; mt < 8; ++mt) {
        const float4 bv = *reinterpret_cast<const float4*>(bias + mt * 16 + quad * 4);
        const float bf[4] = {bv.x, bv.y, bv.z, bv.w};
        union { uint2 v; unsigned short u[4]; } hh, ll;
#pragma unroll
        for (int r = 0; r < 4; ++r) {
            const float v = acc[mt][r] + bf[r];
            const unsigned short h = f2bf(v);
            hh.u[r] = h;
            ll.u[r] = f2bf(v - bf2f(h));
        }
        const int off = erow * 136 + mt * 16 + quad * 4;
        *reinterpret_cast<uint2*>(&XH[off]) = hh.v;
        if (!isK) *reinterpret_cast<uint2*>(&XL[off]) = ll.v;
    }
    __syncthreads();

    // ---- readback + coalesced global stores (round-8 verified layouts) ----
    const int l    = tid & 15;
    const int kthi = tid >> 4;          // 0..15
    if (!isK) {
#pragma unroll
        for (int rr = 0; rr < 4; ++rr) {
            const int row = l + 16 * rr;
            const uint4 ph = *reinterpret_cast<const uint4*>(&XH[row * 136 + kthi * 8]);
            const uint4 pl = *reinterpret_cast<const uint4*>(&XL[row * 136 + kthi * 8]);
            const size_t base = ((size_t)kthi * NROWS + row0 + row) * 8;
            *reinterpret_cast<uint4*>(Qhi + base) = ph;
            *reinterpret_cast<uint4*>(Qlo + base) = pl;
        }
    } else {
#pragma unroll
        for (int rr = 0; rr < 4; ++rr) {
            const int row = l + 16 * rr;
            const int grow = row0 + row;
            const int b    = grow >> 11;
            const int key  = grow & (SEQ - 1);
            const uint4 pk = *reinterpret_cast<const uint4*>(&XH[row * 136 + kthi * 8]);
            const size_t base = (((size_t)(b * 16) + kthi) * SEQ + key) * 8;
            *reinterpret_cast<uint4*>(Kb + base) = pk;
        }
    }
}

// ---------------------------------------------------------------------------
// FUSED scores + entmax (unchanged from round 10 — proven, absmax 0.0039).
// 16 rows x 2048 keys per block, 512 threads (8 waves), 64 KB LDS.
// ---------------------------------------------------------------------------
__global__ void __launch_bounds__(512, 4)
attn_fused(const __bf16* __restrict__ Qhi, const __bf16* __restrict__ Qlo,
           const __bf16* __restrict__ Kb, float* __restrict__ out) {
    __shared__ unsigned int SW[4 * 4098];   // 4 rowgroups x (2048 keys x 2 + pad)
    const int tid  = threadIdx.x;
    const int wv   = tid >> 6;              // 0..7
    const int lane = tid & 63;
    const int l4   = lane & 15;
    const int quad = lane >> 4;             // 0..3
    const int row0 = blockIdx.x * 16;
    const int b    = row0 >> 11;
    const int key0 = wv * 256;

    // ---------------- phase 1: MFMA scores -> LDS ----------------
    {
        floatx4 acc[16];
        const floatx4 zerov = {};
#pragma unroll
        for (int t = 0; t < 16; ++t) acc[t] = zerov;

        const size_t qbase = ((size_t)quad * NROWS + row0 + l4) * 8;
        const size_t kbase = (((size_t)(b * 16) + quad) * SEQ + key0 + l4) * 8;
        const size_t qstep = (size_t)4 * NROWS * 8;   // kt -> kt+1
        const size_t kstep = (size_t)4 * SEQ * 8;

#pragma unroll
        for (int kt = 0; kt < 4; ++kt) {
            const bf16x8 ah = *reinterpret_cast<const bf16x8*>(Qhi + qbase + kt * qstep);
            const bf16x8 al = *reinterpret_cast<const bf16x8*>(Qlo + qbase + kt * qstep);
            const __bf16* kc = Kb + kbase + kt * kstep;
#pragma unroll
            for (int t = 0; t < 16; ++t) {
                const bf16x8 bkv = *reinterpret_cast<const bf16x8*>(kc + (size_t)t * 128);
                acc[t] = __builtin_amdgcn_mfma_f32_16x16x32_bf16(ah, bkv, acc[t], 0, 0, 0);
                acc[t] = __builtin_amdgcn_mfma_f32_16x16x32_bf16(al, bkv, acc[t], 0, 0, 0);
            }
        }
        // C/D: col = l4 (key), row = quad*4 + reg -> reg-quad = rowgroup `quad`
#pragma unroll
        for (int t = 0; t < 16; ++t) {
            union { uint2 v; unsigned short u[4]; } pk;
#pragma unroll
            for (int bb = 0; bb < 4; ++bb) pk.u[bb] = f2h(acc[t][bb]);
            const int key = key0 + t * 16 + l4;
            *reinterpret_cast<uint2*>(&SW[quad * 4098 + 2 * key]) = pk.v;
        }
    }
    __syncthreads();

    // ---------------- phase 2: entmax, 2 rows per wave, interleaved ----------
    const int g  = wv >> 1;                 // rowgroup 0..3
    const int sp = wv & 1;                  // rows 4g+2sp+{0,1}

    const unsigned int* Sw = &SW[g * 4098];
    unsigned int raw[32];
#pragma unroll
    for (int c = 0; c < 32; ++c) raw[c] = Sw[2 * (c * 64 + lane) + sp];

    // split into the two sub-rows' f16x2 key-pair vectors
    half2v z0[16], z1[16];
#pragma unroll
    for (int i = 0; i < 16; ++i) {
        union { unsigned int u; half2v h; } c0, c1;
        c0.u = __builtin_amdgcn_perm(raw[2 * i + 1], raw[2 * i], 0x05040100u);
        c1.u = __builtin_amdgcn_perm(raw[2 * i + 1], raw[2 * i], 0x07060302u);
        z0[i] = c0.h;
        z1[i] = c1.h;
    }

    const half2v hzero = {(_Float16)0.0f, (_Float16)0.0f};

    // row maxes (two independent chains)
    float m0 = -1e30f, m1 = -1e30f;
#pragma unroll
    for (int i = 0; i < 16; ++i) {
        m0 = fmaxf(m0, fmaxf((float)z0[i].x, (float)z0[i].y));
        m1 = fmaxf(m1, fmaxf((float)z1[i].x, (float)z1[i].y));
    }
#pragma unroll
    for (int off = 32; off >= 1; off >>= 1) {
        m0 = fmaxf(m0, __shfl_xor(m0, off, 64));
        m1 = fmaxf(m1, __shfl_xor(m1, off, 64));
    }

    // interleaved bisections: sum max(s - th, 0)^2 = 512, th in [m-1/c, m]
    float lo0 = m0 - THETA_SPAN, hi0 = m0;
    float lo1 = m1 - THETA_SPAN, hi1 = m1;
    for (int it = 0; it < 11; ++it) {
        const float th0 = 0.5f * (lo0 + hi0);
        const float th1 = 0.5f * (lo1 + hi1);
        const _Float16 t0h = (_Float16)th0;
        const _Float16 t1h = (_Float16)th1;
        const half2v n0 = {(_Float16)-t0h, (_Float16)-t0h};
        const half2v n1 = {(_Float16)-t1h, (_Float16)-t1h};
        float f0 = 0.0f, f1 = 0.0f;
#pragma unroll
        for (int i = 0; i < 16; ++i) {
            half2v d0 = z0[i] + n0;
            half2v d1 = z1[i] + n1;
            d0 = __builtin_elementwise_max(d0, hzero);
            d1 = __builtin_elementwise_max(d1, hzero);
            f0 = fdot2acc(d0, d0, f0);
            f1 = fdot2acc(d1, d1, f1);
        }
#pragma unroll
        for (int off = 32; off >= 1; off >>= 1) {
            f0 += __shfl_xor(f0, off, 64);
            f1 += __shfl_xor(f1, off, 64);
        }
        if (f0 >= 512.0f) lo0 = th0; else hi0 = th0;
        if (f1 >= 512.0f) lo1 = th1; else hi1 = th1;
    }
    float th0 = 0.5f * (lo0 + hi0);
    float th1 = 0.5f * (lo1 + hi1);
    th0 = (float)((_Float16)th0);   // evaluate at the quantized theta
    th1 = (float)((_Float16)th1);

    // epilogue: p = max(s-th,0)^2 / 512, f32 coalesced stores
    float* o0 = out + (size_t)(row0 + 4 * g + 2 * sp + 0) * SEQ + lane;
    float* o1 = out + (size_t)(row0 + 4 * g + 2 * sp + 1) * SEQ + lane;
#pragma unroll
    for (int i = 0; i < 16; ++i) {
        const float a0 = fmaxf((float)z0[i].x - th0, 0.0f);
        const float a1 = fmaxf((float)z0[i].y - th0, 0.0f);
        const float b0 = fmaxf((float)z1[i].x - th1, 0.0f);
        const float b1 = fmaxf((float)z1[i].y - th1, 0.0f);
        o0[(size_t)(2 * i) * 64]     = a0 * a0 * (1.0f / 512.0f);
        o0[(size_t)(2 * i + 1) * 64] = a1 * a1 * (1.0f / 512.0f);
        o1[(size_t)(2 * i) * 64]     = b0 * b0 * (1.0f / 512.0f);
        o1[(size_t)(2 * i + 1) * 64] = b1 * b1 * (1.0f / 512.0f);
    }
}

// ---------------------------------------------------------------------------
extern "C" void kernel_launch(void* const* d_in, const int* in_sizes, int n_in,
                              void* d_out, int out_size, void* d_ws, size_t ws_size,
                              hipStream_t stream) {
    const float* x_c = (const float*)d_in[0];
    const float* x_n = (const float*)d_in[1];
    const float* Wq  = (const float*)d_in[2];
    const float* bq  = (const float*)d_in[3];
    const float* Wk  = (const float*)d_in[4];
    const float* bk  = (const float*)d_in[5];
    float* out = (float*)d_out;

    char* ws = (char*)d_ws;
    unsigned short* Qhi = (unsigned short*)ws;                        // 4 MB
    unsigned short* Qlo = (unsigned short*)(ws + ((size_t)4 << 20));  // 4 MB
    unsigned short* Kbl = (unsigned short*)(ws + ((size_t)8 << 20));  // 4 MB

    proj_qk<<<dim3(NROWS / 64, 2), 256, 0, stream>>>(
        x_c, x_n, Wq, bq, Wk, bk, Qhi, Qlo, Kbl);
    attn_fused<<<NROWS / 16, 512, 0, stream>>>(
        (const __bf16*)Qhi, (const __bf16*)Qlo, (const __bf16*)Kbl, out);
}

// Round 12
// 191.078 us; speedup vs baseline: 1.0501x; 1.0132x over previous
//
#include <hip/hip_runtime.h>
#include <hip/hip_bf16.h>

#define BATCH 8
#define SEQ   2048
#define DIM   128
#define NROWS 16384                       // BATCH*SEQ
#define THETA_SPAN 22.62741699796952f     // 2*sqrt(128) = 1/c ; c^2 = 1/512

typedef __bf16    bf16x8   __attribute__((ext_vector_type(8)));
typedef float     floatx4  __attribute__((ext_vector_type(4)));
typedef _Float16  half2v   __attribute__((ext_vector_type(2)));

static __device__ __forceinline__ unsigned short f2bf(float v) {
    union { __hip_bfloat16 h; unsigned short u; } c;
    c.h = __float2bfloat16(v);
    return c.u;
}
static __device__ __forceinline__ float bf2f(unsigned short u) {
    union { unsigned int i; float f; } c;
    c.i = (unsigned int)u << 16;
    return c.f;
}
static __device__ __forceinline__ unsigned short f2h(float v) {
    union { _Float16 h; unsigned short u; } c;
    c.h = (_Float16)v;
    return c.u;
}

#if __has_builtin(__builtin_amdgcn_fdot2)
static __device__ __forceinline__ float fdot2acc(half2v a, half2v b, float c) {
    return __builtin_amdgcn_fdot2(a, b, c, false);
}
#else
static __device__ __forceinline__ float fdot2acc(half2v a, half2v b, float c) {
    return fmaf((float)a.y, (float)b.y, fmaf((float)a.x, (float)b.x, c));
}
#endif

// ---------------------------------------------------------------------------
// MFMA-based Q/K projection (unchanged from round 11 — verified, ~5-6us).
// ---------------------------------------------------------------------------
__global__ void __launch_bounds__(256, 2)
proj_qk(const float* __restrict__ xq, const float* __restrict__ xn,
        const float* __restrict__ Wq, const float* __restrict__ bq,
        const float* __restrict__ Wk, const float* __restrict__ bk,
        unsigned short* __restrict__ Qhi, unsigned short* __restrict__ Qlo,
        unsigned short* __restrict__ Kb) {
    const int isK = blockIdx.y;
    const float* __restrict__ X    = isK ? xn : xq;
    const float* __restrict__ W    = isK ? Wk : Wq;
    const float* __restrict__ bias = isK ? bk : bq;

    __shared__ __align__(16) unsigned short SM[34816];
    unsigned short* XH = SM;            // 64 x 136
    unsigned short* XL = SM + 8704;     // 64 x 136
    unsigned short* WW = SM + 17408;    // 128 x 136

    const int tid  = threadIdx.x;
    const int lane = tid & 63;
    const int wv   = tid >> 6;          // 0..3
    const int l4   = lane & 15;
    const int quad = lane >> 4;         // 0..3
    const int row0 = blockIdx.x * 64;

    // ---- stage X (64x128 f32 -> bf16 hi+lo), coalesced float4 reads ----
#pragma unroll
    for (int i = 0; i < 8; ++i) {
        const int g  = tid + 256 * i;          // g < 2048
        const int r  = g >> 5;
        const int c4 = g & 31;
        const float4 xv = *reinterpret_cast<const float4*>(
            X + (size_t)(row0 + r) * DIM + 4 * c4);
        union { ushort2 v[2]; unsigned short u[4]; } hh, ll;
        const float xf[4] = {xv.x, xv.y, xv.z, xv.w};
#pragma unroll
        for (int j = 0; j < 4; ++j) {
            const unsigned short h = f2bf(xf[j]);
            hh.u[j] = h;
            ll.u[j] = f2bf(xf[j] - bf2f(h));
        }
        *reinterpret_cast<uint2*>(&XH[r * 136 + 4 * c4]) =
            *reinterpret_cast<uint2*>(hh.u);
        *reinterpret_cast<uint2*>(&XL[r * 136 + 4 * c4]) =
            *reinterpret_cast<uint2*>(ll.u);
    }
    // ---- stage W (128x128 f32 -> bf16), coalesced ----
#pragma unroll
    for (int i = 0; i < 16; ++i) {
        const int g  = tid + 256 * i;          // g < 4096
        const int d  = g >> 5;
        const int c4 = g & 31;
        const float4 wvv = *reinterpret_cast<const float4*>(
            W + (size_t)d * DIM + 4 * c4);
        union { uint2 v; unsigned short u[4]; } pw;
        pw.u[0] = f2bf(wvv.x); pw.u[1] = f2bf(wvv.y);
        pw.u[2] = f2bf(wvv.z); pw.u[3] = f2bf(wvv.w);
        *reinterpret_cast<uint2*>(&WW[d * 136 + 4 * c4]) = pw.v;
    }
    __syncthreads();

    // ---- MFMA: acc[mt][reg] = value of (row = wv*16+l4, d = mt*16+quad*4+reg)
    floatx4 acc[8];
    const floatx4 zerov = {};
#pragma unroll
    for (int mt = 0; mt < 8; ++mt) acc[mt] = zerov;

#pragma unroll
    for (int kt = 0; kt < 4; ++kt) {
        const int koff = kt * 32 + quad * 8;
        const bf16x8 xh = *reinterpret_cast<const bf16x8*>(
            &XH[(wv * 16 + l4) * 136 + koff]);
        const bf16x8 xl = *reinterpret_cast<const bf16x8*>(
            &XL[(wv * 16 + l4) * 136 + koff]);
#pragma unroll
        for (int mt = 0; mt < 8; ++mt) {
            const bf16x8 wf = *reinterpret_cast<const bf16x8*>(
                &WW[(mt * 16 + l4) * 136 + koff]);
            acc[mt] = __builtin_amdgcn_mfma_f32_16x16x32_bf16(wf, xh, acc[mt], 0, 0, 0);
            acc[mt] = __builtin_amdgcn_mfma_f32_16x16x32_bf16(wf, xl, acc[mt], 0, 0, 0);
        }
    }

    // ---- epilogue: +bias, convert, pack ushort4 into planes (own rows only)
    const int erow = wv * 16 + l4;      // this lane's output row
#pragma unroll
    for (int mt = 0; mt < 8; ++mt) {
        const float4 bv = *reinterpret_cast<const float4*>(bias + mt * 16 + quad * 4);
        const float bf[4] = {bv.x, bv.y, bv.z, bv.w};
        union { uint2 v; unsigned short u[4]; } hh, ll;
#pragma unroll
        for (int r = 0; r < 4; ++r) {
            const float v = acc[mt][r] + bf[r];
            const unsigned short h = f2bf(v);
            hh.u[r] = h;
            ll.u[r] = f2bf(v - bf2f(h));
        }
        const int off = erow * 136 + mt * 16 + quad * 4;
        *reinterpret_cast<uint2*>(&XH[off]) = hh.v;
        if (!isK) *reinterpret_cast<uint2*>(&XL[off]) = ll.v;
    }
    __syncthreads();

    // ---- readback + coalesced global stores (round-8 verified layouts) ----
    const int l    = tid & 15;
    const int kthi = tid >> 4;          // 0..15
    if (!isK) {
#pragma unroll
        for (int rr = 0; rr < 4; ++rr) {
            const int row = l + 16 * rr;
            const uint4 ph = *reinterpret_cast<const uint4*>(&XH[row * 136 + kthi * 8]);
            const uint4 pl = *reinterpret_cast<const uint4*>(&XL[row * 136 + kthi * 8]);
            const size_t base = ((size_t)kthi * NROWS + row0 + row) * 8;
            *reinterpret_cast<uint4*>(Qhi + base) = ph;
            *reinterpret_cast<uint4*>(Qlo + base) = pl;
        }
    } else {
#pragma unroll
        for (int rr = 0; rr < 4; ++rr) {
            const int row = l + 16 * rr;
            const int grow = row0 + row;
            const int b    = grow >> 11;
            const int key  = grow & (SEQ - 1);
            const uint4 pk = *reinterpret_cast<const uint4*>(&XH[row * 136 + kthi * 8]);
            const size_t base = (((size_t)(b * 16) + kthi) * SEQ + key) * 8;
            *reinterpret_cast<uint4*>(Kb + base) = pk;
        }
    }
}

// ---------------------------------------------------------------------------
// FUSED scores + entmax. Identical to round 10/11 except the tau-solver:
// NEWTON from the left replaces bisection. f(th) = sum max(s-th,0)^2 is
// convex decreasing; from th <= th* the update th += (f-512)/(2g) with
// g = sum max(s-th,0) is monotone increasing and never exceeds th*
// (tangent underestimates a convex function). Start th0 = m - 22.63
// (f(th0) >= (m-th0)^2 = 512). th* <= m - 0.5 always (uniform-row extreme),
// so g >= 0.48 > 0 — no division hazard. 7 iterations (vs 11 bisections);
// piecewise-quadratic f makes Newton exact once the support set stabilizes.
// ---------------------------------------------------------------------------
__global__ void __launch_bounds__(512, 4)
attn_fused(const __bf16* __restrict__ Qhi, const __bf16* __restrict__ Qlo,
           const __bf16* __restrict__ Kb, float* __restrict__ out) {
    __shared__ unsigned int SW[4 * 4098];   // 4 rowgroups x (2048 keys x 2 + pad)
    const int tid  = threadIdx.x;
    const int wv   = tid >> 6;              // 0..7
    const int lane = tid & 63;
    const int l4   = lane & 15;
    const int quad = lane >> 4;             // 0..3
    const int row0 = blockIdx.x * 16;
    const int b    = row0 >> 11;
    const int key0 = wv * 256;

    // ---------------- phase 1: MFMA scores -> LDS ----------------
    {
        floatx4 acc[16];
        const floatx4 zerov = {};
#pragma unroll
        for (int t = 0; t < 16; ++t) acc[t] = zerov;

        const size_t qbase = ((size_t)quad * NROWS + row0 + l4) * 8;
        const size_t kbase = (((size_t)(b * 16) + quad) * SEQ + key0 + l4) * 8;
        const size_t qstep = (size_t)4 * NROWS * 8;   // kt -> kt+1
        const size_t kstep = (size_t)4 * SEQ * 8;

#pragma unroll
        for (int kt = 0; kt < 4; ++kt) {
            const bf16x8 ah = *reinterpret_cast<const bf16x8*>(Qhi + qbase + kt * qstep);
            const bf16x8 al = *reinterpret_cast<const bf16x8*>(Qlo + qbase + kt * qstep);
            const __bf16* kc = Kb + kbase + kt * kstep;
#pragma unroll
            for (int t = 0; t < 16; ++t) {
                const bf16x8 bkv = *reinterpret_cast<const bf16x8*>(kc + (size_t)t * 128);
                acc[t] = __builtin_amdgcn_mfma_f32_16x16x32_bf16(ah, bkv, acc[t], 0, 0, 0);
                acc[t] = __builtin_amdgcn_mfma_f32_16x16x32_bf16(al, bkv, acc[t], 0, 0, 0);
            }
        }
        // C/D: col = l4 (key), row = quad*4 + reg -> reg-quad = rowgroup `quad`
#pragma unroll
        for (int t = 0; t < 16; ++t) {
            union { uint2 v; unsigned short u[4]; } pk;
#pragma unroll
            for (int bb = 0; bb < 4; ++bb) pk.u[bb] = f2h(acc[t][bb]);
            const int key = key0 + t * 16 + l4;
            *reinterpret_cast<uint2*>(&SW[quad * 4098 + 2 * key]) = pk.v;
        }
    }
    __syncthreads();

    // ---------------- phase 2: entmax, 2 rows per wave, interleaved ----------
    const int g  = wv >> 1;                 // rowgroup 0..3
    const int sp = wv & 1;                  // rows 4g+2sp+{0,1}

    const unsigned int* Sw = &SW[g * 4098];
    unsigned int raw[32];
#pragma unroll
    for (int c = 0; c < 32; ++c) raw[c] = Sw[2 * (c * 64 + lane) + sp];

    // split into the two sub-rows' f16x2 key-pair vectors
    half2v z0[16], z1[16];
#pragma unroll
    for (int i = 0; i < 16; ++i) {
        union { unsigned int u; half2v h; } c0, c1;
        c0.u = __builtin_amdgcn_perm(raw[2 * i + 1], raw[2 * i], 0x05040100u);
        c1.u = __builtin_amdgcn_perm(raw[2 * i + 1], raw[2 * i], 0x07060302u);
        z0[i] = c0.h;
        z1[i] = c1.h;
    }

    const half2v hzero = {(_Float16)0.0f, (_Float16)0.0f};
    const half2v hone  = {(_Float16)1.0f, (_Float16)1.0f};

    // row maxes (two independent chains)
    float m0 = -1e30f, m1 = -1e30f;
#pragma unroll
    for (int i = 0; i < 16; ++i) {
        m0 = fmaxf(m0, fmaxf((float)z0[i].x, (float)z0[i].y));
        m1 = fmaxf(m1, fmaxf((float)z1[i].x, (float)z1[i].y));
    }
#pragma unroll
    for (int off = 32; off >= 1; off >>= 1) {
        m0 = fmaxf(m0, __shfl_xor(m0, off, 64));
        m1 = fmaxf(m1, __shfl_xor(m1, off, 64));
    }

    // Newton: th += (f - 512)/(2g); monotone from the left, 7 iterations
    float th0 = m0 - THETA_SPAN;
    float th1 = m1 - THETA_SPAN;
    for (int it = 0; it < 7; ++it) {
        const _Float16 t0h = (_Float16)th0;
        const _Float16 t1h = (_Float16)th1;
        const half2v n0 = {(_Float16)-t0h, (_Float16)-t0h};
        const half2v n1 = {(_Float16)-t1h, (_Float16)-t1h};
        float f0 = 0.0f, f1 = 0.0f, g0 = 0.0f, g1 = 0.0f;
#pragma unroll
        for (int i = 0; i < 16; ++i) {
            half2v d0 = z0[i] + n0;
            half2v d1 = z1[i] + n1;
            d0 = __builtin_elementwise_max(d0, hzero);
            d1 = __builtin_elementwise_max(d1, hzero);
            f0 = fdot2acc(d0, d0, f0);
            f1 = fdot2acc(d1, d1, f1);
            g0 = fdot2acc(d0, hone, g0);
            g1 = fdot2acc(d1, hone, g1);
        }
#pragma unroll
        for (int off = 32; off >= 1; off >>= 1) {
            f0 += __shfl_xor(f0, off, 64);
            f1 += __shfl_xor(f1, off, 64);
            g0 += __shfl_xor(g0, off, 64);
            g1 += __shfl_xor(g1, off, 64);
        }
        th0 += (f0 - 512.0f) / (2.0f * g0);
        th1 += (f1 - 512.0f) / (2.0f * g1);
    }

    // epilogue: p = max(s-th,0)^2 / 512, f32 coalesced stores
    float* o0 = out + (size_t)(row0 + 4 * g + 2 * sp + 0) * SEQ + lane;
    float* o1 = out + (size_t)(row0 + 4 * g + 2 * sp + 1) * SEQ + lane;
#pragma unroll
    for (int i = 0; i < 16; ++i) {
        const float a0 = fmaxf((float)z0[i].x - th0, 0.0f);
        const float a1 = fmaxf((float)z0[i].y - th0, 0.0f);
        const float b0 = fmaxf((float)z1[i].x - th1, 0.0f);
        const float b1 = fmaxf((float)z1[i].y - th1, 0.0f);
        o0[(size_t)(2 * i) * 64]     = a0 * a0 * (1.0f / 512.0f);
        o0[(size_t)(2 * i + 1) * 64] = a1 * a1 * (1.0f / 512.0f);
        o1[(size_t)(2 * i) * 64]     = b0 * b0 * (1.0f / 512.0f);
        o1[(size_t)(2 * i + 1) * 64] = b1 * b1 * (1.0f / 512.0f);
    }
}

// ---------------------------------------------------------------------------
extern "C" void kernel_launch(void* const* d_in, const int* in_sizes, int n_in,
                              void* d_out, int out_size, void* d_ws, size_t ws_size,
                              hipStream_t stream) {
    const float* x_c = (const float*)d_in[0];
    const float* x_n = (const float*)d_in[1];
    const float* Wq  = (const float*)d_in[2];
    const float* bq  = (const float*)d_in[3];
    const float* Wk  = (const float*)d_in[4];
    const float* bk  = (const float*)d_in[5];
    float* out = (float*)d_out;

    char* ws = (char*)d_ws;
    unsigned short* Qhi = (unsigned short*)ws;                        // 4 MB
    unsigned short* Qlo = (unsigned short*)(ws + ((size_t)4 << 20));  // 4 MB
    unsigned short* Kbl = (unsigned short*)(ws + ((size_t)8 << 20));  // 4 MB

    proj_qk<<<dim3(NROWS / 64, 2), 256, 0, stream>>>(
        x_c, x_n, Wq, bq, Wk, bk, Qhi, Qlo, Kbl);
    attn_fused<<<NROWS / 16, 512, 0, stream>>>(
        (const __bf16*)Qhi, (const __bf16*)Qlo, (const __bf16*)Kbl, out);
}

// Round 13
// 186.211 us; speedup vs baseline: 1.0775x; 1.0261x over previous
//
#include <hip/hip_runtime.h>
#include <hip/hip_bf16.h>

#define BATCH 8
#define SEQ   2048
#define DIM   128
#define NROWS 16384                       // BATCH*SEQ
#define THETA_SPAN 22.62741699796952f     // 2*sqrt(128) = 1/c ; c^2 = 1/512

typedef __bf16    bf16x8   __attribute__((ext_vector_type(8)));
typedef float     floatx4  __attribute__((ext_vector_type(4)));
typedef _Float16  half2v   __attribute__((ext_vector_type(2)));

static __device__ __forceinline__ unsigned short f2bf(float v) {
    union { __hip_bfloat16 h; unsigned short u; } c;
    c.h = __float2bfloat16(v);
    return c.u;
}
static __device__ __forceinline__ float bf2f(unsigned short u) {
    union { unsigned int i; float f; } c;
    c.i = (unsigned int)u << 16;
    return c.f;
}
static __device__ __forceinline__ unsigned short f2h(float v) {
    union { _Float16 h; unsigned short u; } c;
    c.h = (_Float16)v;
    return c.u;
}

#if __has_builtin(__builtin_amdgcn_fdot2)
static __device__ __forceinline__ float fdot2acc(half2v a, half2v b, float c) {
    return __builtin_amdgcn_fdot2(a, b, c, false);
}
#else
static __device__ __forceinline__ float fdot2acc(half2v a, half2v b, float c) {
    return fmaf((float)a.y, (float)b.y, fmaf((float)a.x, (float)b.x, c));
}
#endif

// ---------------------------------------------------------------------------
// MFMA-based Q/K projection. Round-12 verified structure; change: Q is now
// stored as a SINGLE bf16 plane (hi/lo split dropped — f16 score quantization
// already dominates the error budget; bf16-Q adds ~0.007 rms raw-score vs
// 0.008 existing). X is still staged hi+lo so the GEMM itself is f32-accurate;
// only the final Q/K rounding to bf16 remains.
// ---------------------------------------------------------------------------
__global__ void __launch_bounds__(256, 2)
proj_qk(const float* __restrict__ xq, const float* __restrict__ xn,
        const float* __restrict__ Wq, const float* __restrict__ bq,
        const float* __restrict__ Wk, const float* __restrict__ bk,
        unsigned short* __restrict__ Qb, unsigned short* __restrict__ Kb) {
    const int isK = blockIdx.y;
    const float* __restrict__ X    = isK ? xn : xq;
    const float* __restrict__ W    = isK ? Wk : Wq;
    const float* __restrict__ bias = isK ? bk : bq;

    __shared__ __align__(16) unsigned short SM[34816];
    unsigned short* XH = SM;            // 64 x 136
    unsigned short* XL = SM + 8704;     // 64 x 136
    unsigned short* WW = SM + 17408;    // 128 x 136

    const int tid  = threadIdx.x;
    const int lane = tid & 63;
    const int wv   = tid >> 6;          // 0..3
    const int l4   = lane & 15;
    const int quad = lane >> 4;         // 0..3
    const int row0 = blockIdx.x * 64;

    // ---- stage X (64x128 f32 -> bf16 hi+lo), coalesced float4 reads ----
#pragma unroll
    for (int i = 0; i < 8; ++i) {
        const int g  = tid + 256 * i;          // g < 2048
        const int r  = g >> 5;
        const int c4 = g & 31;
        const float4 xv = *reinterpret_cast<const float4*>(
            X + (size_t)(row0 + r) * DIM + 4 * c4);
        union { ushort2 v[2]; unsigned short u[4]; } hh, ll;
        const float xf[4] = {xv.x, xv.y, xv.z, xv.w};
#pragma unroll
        for (int j = 0; j < 4; ++j) {
            const unsigned short h = f2bf(xf[j]);
            hh.u[j] = h;
            ll.u[j] = f2bf(xf[j] - bf2f(h));
        }
        *reinterpret_cast<uint2*>(&XH[r * 136 + 4 * c4]) =
            *reinterpret_cast<uint2*>(hh.u);
        *reinterpret_cast<uint2*>(&XL[r * 136 + 4 * c4]) =
            *reinterpret_cast<uint2*>(ll.u);
    }
    // ---- stage W (128x128 f32 -> bf16), coalesced ----
#pragma unroll
    for (int i = 0; i < 16; ++i) {
        const int g  = tid + 256 * i;          // g < 4096
        const int d  = g >> 5;
        const int c4 = g & 31;
        const float4 wvv = *reinterpret_cast<const float4*>(
            W + (size_t)d * DIM + 4 * c4);
        union { uint2 v; unsigned short u[4]; } pw;
        pw.u[0] = f2bf(wvv.x); pw.u[1] = f2bf(wvv.y);
        pw.u[2] = f2bf(wvv.z); pw.u[3] = f2bf(wvv.w);
        *reinterpret_cast<uint2*>(&WW[d * 136 + 4 * c4]) = pw.v;
    }
    __syncthreads();

    // ---- MFMA: acc[mt][reg] = value of (row = wv*16+l4, d = mt*16+quad*4+reg)
    floatx4 acc[8];
    const floatx4 zerov = {};
#pragma unroll
    for (int mt = 0; mt < 8; ++mt) acc[mt] = zerov;

#pragma unroll
    for (int kt = 0; kt < 4; ++kt) {
        const int koff = kt * 32 + quad * 8;
        const bf16x8 xh = *reinterpret_cast<const bf16x8*>(
            &XH[(wv * 16 + l4) * 136 + koff]);
        const bf16x8 xl = *reinterpret_cast<const bf16x8*>(
            &XL[(wv * 16 + l4) * 136 + koff]);
#pragma unroll
        for (int mt = 0; mt < 8; ++mt) {
            const bf16x8 wf = *reinterpret_cast<const bf16x8*>(
                &WW[(mt * 16 + l4) * 136 + koff]);
            acc[mt] = __builtin_amdgcn_mfma_f32_16x16x32_bf16(wf, xh, acc[mt], 0, 0, 0);
            acc[mt] = __builtin_amdgcn_mfma_f32_16x16x32_bf16(wf, xl, acc[mt], 0, 0, 0);
        }
    }

    // ---- epilogue: +bias, round once to bf16, pack into XH plane (own rows)
    const int erow = wv * 16 + l4;      // this lane's output row
#pragma unroll
    for (int mt = 0; mt < 8; ++mt) {
        const float4 bv = *reinterpret_cast<const float4*>(bias + mt * 16 + quad * 4);
        const float bf[4] = {bv.x, bv.y, bv.z, bv.w};
        union { uint2 v; unsigned short u[4]; } hh;
#pragma unroll
        for (int r = 0; r < 4; ++r) hh.u[r] = f2bf(acc[mt][r] + bf[r]);
        *reinterpret_cast<uint2*>(&XH[erow * 136 + mt * 16 + quad * 4]) = hh.v;
    }
    __syncthreads();

    // ---- readback + coalesced global stores (round-8 verified layouts) ----
    const int l    = tid & 15;
    const int kthi = tid >> 4;          // 0..15
    if (!isK) {
#pragma unroll
        for (int rr = 0; rr < 4; ++rr) {
            const int row = l + 16 * rr;
            const uint4 ph = *reinterpret_cast<const uint4*>(&XH[row * 136 + kthi * 8]);
            const size_t base = ((size_t)kthi * NROWS + row0 + row) * 8;
            *reinterpret_cast<uint4*>(Qb + base) = ph;
        }
    } else {
#pragma unroll
        for (int rr = 0; rr < 4; ++rr) {
            const int row = l + 16 * rr;
            const int grow = row0 + row;
            const int b    = grow >> 11;
            const int key  = grow & (SEQ - 1);
            const uint4 pk = *reinterpret_cast<const uint4*>(&XH[row * 136 + kthi * 8]);
            const size_t base = (((size_t)(b * 16) + kthi) * SEQ + key) * 8;
            *reinterpret_cast<uint4*>(Kb + base) = pk;
        }
    }
}

// ---------------------------------------------------------------------------
// FUSED scores + entmax. Round-12 structure; changes: (1) single-bf16 Q
// (one MFMA per tile instead of two — halves matrix work and Q traffic);
// (2) output via nontemporal stores (134 MB never re-read; keep L2 for the
// K stream). Newton solver unchanged (7 iters, verified exact-converged).
// ---------------------------------------------------------------------------
__global__ void __launch_bounds__(512, 4)
attn_fused(const __bf16* __restrict__ Qb, const __bf16* __restrict__ Kb,
           float* __restrict__ out) {
    __shared__ unsigned int SW[4 * 4098];   // 4 rowgroups x (2048 keys x 2 + pad)
    const int tid  = threadIdx.x;
    const int wv   = tid >> 6;              // 0..7
    const int lane = tid & 63;
    const int l4   = lane & 15;
    const int quad = lane >> 4;             // 0..3
    const int row0 = blockIdx.x * 16;
    const int b    = row0 >> 11;
    const int key0 = wv * 256;

    // ---------------- phase 1: MFMA scores -> LDS ----------------
    {
        floatx4 acc[16];
        const floatx4 zerov = {};
#pragma unroll
        for (int t = 0; t < 16; ++t) acc[t] = zerov;

        const size_t qbase = ((size_t)quad * NROWS + row0 + l4) * 8;
        const size_t kbase = (((size_t)(b * 16) + quad) * SEQ + key0 + l4) * 8;
        const size_t qstep = (size_t)4 * NROWS * 8;   // kt -> kt+1
        const size_t kstep = (size_t)4 * SEQ * 8;

#pragma unroll
        for (int kt = 0; kt < 4; ++kt) {
            const bf16x8 ah = *reinterpret_cast<const bf16x8*>(Qb + qbase + kt * qstep);
            const __bf16* kc = Kb + kbase + kt * kstep;
#pragma unroll
            for (int t = 0; t < 16; ++t) {
                const bf16x8 bkv = *reinterpret_cast<const bf16x8*>(kc + (size_t)t * 128);
                acc[t] = __builtin_amdgcn_mfma_f32_16x16x32_bf16(ah, bkv, acc[t], 0, 0, 0);
            }
        }
        // C/D: col = l4 (key), row = quad*4 + reg -> reg-quad = rowgroup `quad`
#pragma unroll
        for (int t = 0; t < 16; ++t) {
            union { uint2 v; unsigned short u[4]; } pk;
#pragma unroll
            for (int bb = 0; bb < 4; ++bb) pk.u[bb] = f2h(acc[t][bb]);
            const int key = key0 + t * 16 + l4;
            *reinterpret_cast<uint2*>(&SW[quad * 4098 + 2 * key]) = pk.v;
        }
    }
    __syncthreads();

    // ---------------- phase 2: entmax, 2 rows per wave, interleaved ----------
    const int g  = wv >> 1;                 // rowgroup 0..3
    const int sp = wv & 1;                  // rows 4g+2sp+{0,1}

    const unsigned int* Sw = &SW[g * 4098];
    unsigned int raw[32];
#pragma unroll
    for (int c = 0; c < 32; ++c) raw[c] = Sw[2 * (c * 64 + lane) + sp];

    // split into the two sub-rows' f16x2 key-pair vectors
    half2v z0[16], z1[16];
#pragma unroll
    for (int i = 0; i < 16; ++i) {
        union { unsigned int u; half2v h; } c0, c1;
        c0.u = __builtin_amdgcn_perm(raw[2 * i + 1], raw[2 * i], 0x05040100u);
        c1.u = __builtin_amdgcn_perm(raw[2 * i + 1], raw[2 * i], 0x07060302u);
        z0[i] = c0.h;
        z1[i] = c1.h;
    }

    const half2v hzero = {(_Float16)0.0f, (_Float16)0.0f};
    const half2v hone  = {(_Float16)1.0f, (_Float16)1.0f};

    // row maxes (two independent chains)
    float m0 = -1e30f, m1 = -1e30f;
#pragma unroll
    for (int i = 0; i < 16; ++i) {
        m0 = fmaxf(m0, fmaxf((float)z0[i].x, (float)z0[i].y));
        m1 = fmaxf(m1, fmaxf((float)z1[i].x, (float)z1[i].y));
    }
#pragma unroll
    for (int off = 32; off >= 1; off >>= 1) {
        m0 = fmaxf(m0, __shfl_xor(m0, off, 64));
        m1 = fmaxf(m1, __shfl_xor(m1, off, 64));
    }

    // Newton: th += (f - 512)/(2g); monotone from the left, 7 iterations
    float th0 = m0 - THETA_SPAN;
    float th1 = m1 - THETA_SPAN;
    for (int it = 0; it < 7; ++it) {
        const _Float16 t0h = (_Float16)th0;
        const _Float16 t1h = (_Float16)th1;
        const half2v n0 = {(_Float16)-t0h, (_Float16)-t0h};
        const half2v n1 = {(_Float16)-t1h, (_Float16)-t1h};
        float f0 = 0.0f, f1 = 0.0f, g0 = 0.0f, g1 = 0.0f;
#pragma unroll
        for (int i = 0; i < 16; ++i) {
            half2v d0 = z0[i] + n0;
            half2v d1 = z1[i] + n1;
            d0 = __builtin_elementwise_max(d0, hzero);
            d1 = __builtin_elementwise_max(d1, hzero);
            f0 = fdot2acc(d0, d0, f0);
            f1 = fdot2acc(d1, d1, f1);
            g0 = fdot2acc(d0, hone, g0);
            g1 = fdot2acc(d1, hone, g1);
        }
#pragma unroll
        for (int off = 32; off >= 1; off >>= 1) {
            f0 += __shfl_xor(f0, off, 64);
            f1 += __shfl_xor(f1, off, 64);
            g0 += __shfl_xor(g0, off, 64);
            g1 += __shfl_xor(g1, off, 64);
        }
        th0 += (f0 - 512.0f) / (2.0f * g0);
        th1 += (f1 - 512.0f) / (2.0f * g1);
    }

    // epilogue: p = max(s-th,0)^2 / 512, nontemporal f32 coalesced stores
    float* o0 = out + (size_t)(row0 + 4 * g + 2 * sp + 0) * SEQ + lane;
    float* o1 = out + (size_t)(row0 + 4 * g + 2 * sp + 1) * SEQ + lane;
#pragma unroll
    for (int i = 0; i < 16; ++i) {
        const float a0 = fmaxf((float)z0[i].x - th0, 0.0f);
        const float a1 = fmaxf((float)z0[i].y - th0, 0.0f);
        const float b0 = fmaxf((float)z1[i].x - th1, 0.0f);
        const float b1 = fmaxf((float)z1[i].y - th1, 0.0f);
        __builtin_nontemporal_store(a0 * a0 * (1.0f / 512.0f), o0 + (size_t)(2 * i) * 64);
        __builtin_nontemporal_store(a1 * a1 * (1.0f / 512.0f), o0 + (size_t)(2 * i + 1) * 64);
        __builtin_nontemporal_store(b0 * b0 * (1.0f / 512.0f), o1 + (size_t)(2 * i) * 64);
        __builtin_nontemporal_store(b1 * b1 * (1.0f / 512.0f), o1 + (size_t)(2 * i + 1) * 64);
    }
}

// ---------------------------------------------------------------------------
extern "C" void kernel_launch(void* const* d_in, const int* in_sizes, int n_in,
                              void* d_out, int out_size, void* d_ws, size_t ws_size,
                              hipStream_t stream) {
    const float* x_c = (const float*)d_in[0];
    const float* x_n = (const float*)d_in[1];
    const float* Wq  = (const float*)d_in[2];
    const float* bq  = (const float*)d_in[3];
    const float* Wk  = (const float*)d_in[4];
    const float* bk  = (const float*)d_in[5];
    float* out = (float*)d_out;

    char* ws = (char*)d_ws;
    unsigned short* Qbl = (unsigned short*)ws;                        // 4 MB
    unsigned short* Kbl = (unsigned short*)(ws + ((size_t)4 << 20));  // 4 MB

    proj_qk<<<dim3(NROWS / 64, 2), 256, 0, stream>>>(
        x_c, x_n, Wq, bq, Wk, bk, Qbl, Kbl);
    attn_fused<<<NROWS / 16, 512, 0, stream>>>(
        (const __bf16*)Qbl, (const __bf16*)Kbl, out);
}

// Round 14
// 184.322 us; speedup vs baseline: 1.0886x; 1.0102x over previous
//
#include <hip/hip_runtime.h>
#include <hip/hip_bf16.h>

#define BATCH 8
#define SEQ   2048
#define DIM   128
#define NROWS 16384                       // BATCH*SEQ
#define THETA_SPAN 22.62741699796952f     // 2*sqrt(128) = 1/c ; c^2 = 1/512

typedef __bf16    bf16x8   __attribute__((ext_vector_type(8)));
typedef float     floatx4  __attribute__((ext_vector_type(4)));
typedef _Float16  half2v   __attribute__((ext_vector_type(2)));

static __device__ __forceinline__ unsigned short f2bf(float v) {
    union { __hip_bfloat16 h; unsigned short u; } c;
    c.h = __float2bfloat16(v);
    return c.u;
}
static __device__ __forceinline__ float bf2f(unsigned short u) {
    union { unsigned int i; float f; } c;
    c.i = (unsigned int)u << 16;
    return c.f;
}
static __device__ __forceinline__ unsigned int f2h2(float a, float b) {
    union { _Float16 h; unsigned short u; } ca, cb;
    ca.h = (_Float16)a;
    cb.h = (_Float16)b;
    return (unsigned int)ca.u | ((unsigned int)cb.u << 16);
}

#if __has_builtin(__builtin_amdgcn_fdot2)
static __device__ __forceinline__ float fdot2acc(half2v a, half2v b, float c) {
    return __builtin_amdgcn_fdot2(a, b, c, false);
}
#else
static __device__ __forceinline__ float fdot2acc(half2v a, half2v b, float c) {
    return fmaf((float)a.y, (float)b.y, fmaf((float)a.x, (float)b.x, c));
}
#endif

// ---------------------------------------------------------------------------
// MFMA-based Q/K projection (unchanged from round 13 — verified).
// ---------------------------------------------------------------------------
__global__ void __launch_bounds__(256, 2)
proj_qk(const float* __restrict__ xq, const float* __restrict__ xn,
        const float* __restrict__ Wq, const float* __restrict__ bq,
        const float* __restrict__ Wk, const float* __restrict__ bk,
        unsigned short* __restrict__ Qb, unsigned short* __restrict__ Kb) {
    const int isK = blockIdx.y;
    const float* __restrict__ X    = isK ? xn : xq;
    const float* __restrict__ W    = isK ? Wk : Wq;
    const float* __restrict__ bias = isK ? bk : bq;

    __shared__ __align__(16) unsigned short SM[34816];
    unsigned short* XH = SM;            // 64 x 136
    unsigned short* XL = SM + 8704;     // 64 x 136
    unsigned short* WW = SM + 17408;    // 128 x 136

    const int tid  = threadIdx.x;
    const int lane = tid & 63;
    const int wv   = tid >> 6;          // 0..3
    const int l4   = lane & 15;
    const int quad = lane >> 4;         // 0..3
    const int row0 = blockIdx.x * 64;

    // ---- stage X (64x128 f32 -> bf16 hi+lo), coalesced float4 reads ----
#pragma unroll
    for (int i = 0; i < 8; ++i) {
        const int g  = tid + 256 * i;          // g < 2048
        const int r  = g >> 5;
        const int c4 = g & 31;
        const float4 xv = *reinterpret_cast<const float4*>(
            X + (size_t)(row0 + r) * DIM + 4 * c4);
        union { ushort2 v[2]; unsigned short u[4]; } hh, ll;
        const float xf[4] = {xv.x, xv.y, xv.z, xv.w};
#pragma unroll
        for (int j = 0; j < 4; ++j) {
            const unsigned short h = f2bf(xf[j]);
            hh.u[j] = h;
            ll.u[j] = f2bf(xf[j] - bf2f(h));
        }
        *reinterpret_cast<uint2*>(&XH[r * 136 + 4 * c4]) =
            *reinterpret_cast<uint2*>(hh.u);
        *reinterpret_cast<uint2*>(&XL[r * 136 + 4 * c4]) =
            *reinterpret_cast<uint2*>(ll.u);
    }
    // ---- stage W (128x128 f32 -> bf16), coalesced ----
#pragma unroll
    for (int i = 0; i < 16; ++i) {
        const int g  = tid + 256 * i;          // g < 4096
        const int d  = g >> 5;
        const int c4 = g & 31;
        const float4 wvv = *reinterpret_cast<const float4*>(
            W + (size_t)d * DIM + 4 * c4);
        union { uint2 v; unsigned short u[4]; } pw;
        pw.u[0] = f2bf(wvv.x); pw.u[1] = f2bf(wvv.y);
        pw.u[2] = f2bf(wvv.z); pw.u[3] = f2bf(wvv.w);
        *reinterpret_cast<uint2*>(&WW[d * 136 + 4 * c4]) = pw.v;
    }
    __syncthreads();

    // ---- MFMA: acc[mt][reg] = value of (row = wv*16+l4, d = mt*16+quad*4+reg)
    floatx4 acc[8];
    const floatx4 zerov = {};
#pragma unroll
    for (int mt = 0; mt < 8; ++mt) acc[mt] = zerov;

#pragma unroll
    for (int kt = 0; kt < 4; ++kt) {
        const int koff = kt * 32 + quad * 8;
        const bf16x8 xh = *reinterpret_cast<const bf16x8*>(
            &XH[(wv * 16 + l4) * 136 + koff]);
        const bf16x8 xl = *reinterpret_cast<const bf16x8*>(
            &XL[(wv * 16 + l4) * 136 + koff]);
#pragma unroll
        for (int mt = 0; mt < 8; ++mt) {
            const bf16x8 wf = *reinterpret_cast<const bf16x8*>(
                &WW[(mt * 16 + l4) * 136 + koff]);
            acc[mt] = __builtin_amdgcn_mfma_f32_16x16x32_bf16(wf, xh, acc[mt], 0, 0, 0);
            acc[mt] = __builtin_amdgcn_mfma_f32_16x16x32_bf16(wf, xl, acc[mt], 0, 0, 0);
        }
    }

    // ---- epilogue: +bias, round once to bf16, pack into XH plane (own rows)
    const int erow = wv * 16 + l4;      // this lane's output row
#pragma unroll
    for (int mt = 0; mt < 8; ++mt) {
        const float4 bv = *reinterpret_cast<const float4*>(bias + mt * 16 + quad * 4);
        const float bf[4] = {bv.x, bv.y, bv.z, bv.w};
        union { uint2 v; unsigned short u[4]; } hh;
#pragma unroll
        for (int r = 0; r < 4; ++r) hh.u[r] = f2bf(acc[mt][r] + bf[r]);
        *reinterpret_cast<uint2*>(&XH[erow * 136 + mt * 16 + quad * 4]) = hh.v;
    }
    __syncthreads();

    // ---- readback + coalesced global stores (round-8 verified layouts) ----
    const int l    = tid & 15;
    const int kthi = tid >> 4;          // 0..15
    if (!isK) {
#pragma unroll
        for (int rr = 0; rr < 4; ++rr) {
            const int row = l + 16 * rr;
            const uint4 ph = *reinterpret_cast<const uint4*>(&XH[row * 136 + kthi * 8]);
            const size_t base = ((size_t)kthi * NROWS + row0 + row) * 8;
            *reinterpret_cast<uint4*>(Qb + base) = ph;
        }
    } else {
#pragma unroll
        for (int rr = 0; rr < 4; ++rr) {
            const int row = l + 16 * rr;
            const int grow = row0 + row;
            const int b    = grow >> 11;
            const int key  = grow & (SEQ - 1);
            const uint4 pk = *reinterpret_cast<const uint4*>(&XH[row * 136 + kthi * 8]);
            const size_t base = (((size_t)(b * 16) + kthi) * SEQ + key) * 8;
            *reinterpret_cast<uint4*>(Kb + base) = pk;
        }
    }
}

// ---------------------------------------------------------------------------
// FUSED scores + entmax. Round-13 math, NEW LDS layout: 8 SUBPLANES of 2056
// dwords; plane p = 2*quad+sp holds rows {4*quad+2*sp, +1} as f16 pairs, one
// dword per key. Old layout strided lanes by 2 dwords -> lanes {0,16,32,48}
// shared a bank (4-way conflict, 1.58x — G4) on all 32 phase-2 reads, and
// phase-1 b64 writes sat on even banks only. New layout: phase-2 reads are
// stride-1 (2-way, free); phase-1 b32 writes per quad are stride-1 with
// planes offset 8 banks (2-way, free). Values/order bit-identical to r13.
// LDS 8*2056*4 = 65792 B -> still 2 blocks/CU.
// ---------------------------------------------------------------------------
__global__ void __launch_bounds__(512, 4)
attn_fused(const __bf16* __restrict__ Qb, const __bf16* __restrict__ Kb,
           float* __restrict__ out) {
    __shared__ unsigned int SW[8 * 2056];
    const int tid  = threadIdx.x;
    const int wv   = tid >> 6;              // 0..7
    const int lane = tid & 63;
    const int l4   = lane & 15;
    const int quad = lane >> 4;             // 0..3
    const int row0 = blockIdx.x * 16;
    const int b    = row0 >> 11;
    const int key0 = wv * 256;

    // ---------------- phase 1: MFMA scores -> LDS subplanes ----------------
    {
        floatx4 acc[16];
        const floatx4 zerov = {};
#pragma unroll
        for (int t = 0; t < 16; ++t) acc[t] = zerov;

        const size_t qbase = ((size_t)quad * NROWS + row0 + l4) * 8;
        const size_t kbase = (((size_t)(b * 16) + quad) * SEQ + key0 + l4) * 8;
        const size_t qstep = (size_t)4 * NROWS * 8;   // kt -> kt+1
        const size_t kstep = (size_t)4 * SEQ * 8;

#pragma unroll
        for (int kt = 0; kt < 4; ++kt) {
            const bf16x8 ah = *reinterpret_cast<const bf16x8*>(Qb + qbase + kt * qstep);
            const __bf16* kc = Kb + kbase + kt * kstep;
#pragma unroll
            for (int t = 0; t < 16; ++t) {
                const bf16x8 bkv = *reinterpret_cast<const bf16x8*>(kc + (size_t)t * 128);
                acc[t] = __builtin_amdgcn_mfma_f32_16x16x32_bf16(ah, bkv, acc[t], 0, 0, 0);
            }
        }
        // C/D: col = l4 (key), row = quad*4 + reg. dword0 = rows {4q, 4q+1},
        // dword1 = rows {4q+2, 4q+3} -> planes 2q and 2q+1 at [key].
#pragma unroll
        for (int t = 0; t < 16; ++t) {
            const int key = key0 + t * 16 + l4;
            SW[(2 * quad + 0) * 2056 + key] = f2h2(acc[t][0], acc[t][1]);
            SW[(2 * quad + 1) * 2056 + key] = f2h2(acc[t][2], acc[t][3]);
        }
    }
    __syncthreads();

    // ---------------- phase 2: entmax, 2 rows per wave, interleaved ----------
    const int g  = wv >> 1;                 // rowgroup 0..3
    const int sp = wv & 1;                  // rows 4g+2sp+{0,1}

    const unsigned int* Sw = &SW[(2 * g + sp) * 2056];
    unsigned int raw[32];
#pragma unroll
    for (int c = 0; c < 32; ++c) raw[c] = Sw[c * 64 + lane];   // stride-1: no conflict

    // split into the two sub-rows' f16x2 key-pair vectors
    half2v z0[16], z1[16];
#pragma unroll
    for (int i = 0; i < 16; ++i) {
        union { unsigned int u; half2v h; } c0, c1;
        c0.u = __builtin_amdgcn_perm(raw[2 * i + 1], raw[2 * i], 0x05040100u);
        c1.u = __builtin_amdgcn_perm(raw[2 * i + 1], raw[2 * i], 0x07060302u);
        z0[i] = c0.h;
        z1[i] = c1.h;
    }

    const half2v hzero = {(_Float16)0.0f, (_Float16)0.0f};
    const half2v hone  = {(_Float16)1.0f, (_Float16)1.0f};

    // row maxes (two independent chains)
    float m0 = -1e30f, m1 = -1e30f;
#pragma unroll
    for (int i = 0; i < 16; ++i) {
        m0 = fmaxf(m0, fmaxf((float)z0[i].x, (float)z0[i].y));
        m1 = fmaxf(m1, fmaxf((float)z1[i].x, (float)z1[i].y));
    }
#pragma unroll
    for (int off = 32; off >= 1; off >>= 1) {
        m0 = fmaxf(m0, __shfl_xor(m0, off, 64));
        m1 = fmaxf(m1, __shfl_xor(m1, off, 64));
    }

    // Newton: th += (f - 512)/(2g); monotone from the left, 7 iterations
    float th0 = m0 - THETA_SPAN;
    float th1 = m1 - THETA_SPAN;
    for (int it = 0; it < 7; ++it) {
        const _Float16 t0h = (_Float16)th0;
        const _Float16 t1h = (_Float16)th1;
        const half2v n0 = {(_Float16)-t0h, (_Float16)-t0h};
        const half2v n1 = {(_Float16)-t1h, (_Float16)-t1h};
        float f0 = 0.0f, f1 = 0.0f, g0 = 0.0f, g1 = 0.0f;
#pragma unroll
        for (int i = 0; i < 16; ++i) {
            half2v d0 = z0[i] + n0;
            half2v d1 = z1[i] + n1;
            d0 = __builtin_elementwise_max(d0, hzero);
            d1 = __builtin_elementwise_max(d1, hzero);
            f0 = fdot2acc(d0, d0, f0);
            f1 = fdot2acc(d1, d1, f1);
            g0 = fdot2acc(d0, hone, g0);
            g1 = fdot2acc(d1, hone, g1);
        }
#pragma unroll
        for (int off = 32; off >= 1; off >>= 1) {
            f0 += __shfl_xor(f0, off, 64);
            f1 += __shfl_xor(f1, off, 64);
            g0 += __shfl_xor(g0, off, 64);
            g1 += __shfl_xor(g1, off, 64);
        }
        th0 += (f0 - 512.0f) / (2.0f * g0);
        th1 += (f1 - 512.0f) / (2.0f * g1);
    }

    // epilogue: p = max(s-th,0)^2 / 512, nontemporal f32 coalesced stores
    float* o0 = out + (size_t)(row0 + 4 * g + 2 * sp + 0) * SEQ + lane;
    float* o1 = out + (size_t)(row0 + 4 * g + 2 * sp + 1) * SEQ + lane;
#pragma unroll
    for (int i = 0; i < 16; ++i) {
        const float a0 = fmaxf((float)z0[i].x - th0, 0.0f);
        const float a1 = fmaxf((float)z0[i].y - th0, 0.0f);
        const float b0 = fmaxf((float)z1[i].x - th1, 0.0f);
        const float b1 = fmaxf((float)z1[i].y - th1, 0.0f);
        __builtin_nontemporal_store(a0 * a0 * (1.0f / 512.0f), o0 + (size_t)(2 * i) * 64);
        __builtin_nontemporal_store(a1 * a1 * (1.0f / 512.0f), o0 + (size_t)(2 * i + 1) * 64);
        __builtin_nontemporal_store(b0 * b0 * (1.0f / 512.0f), o1 + (size_t)(2 * i) * 64);
        __builtin_nontemporal_store(b1 * b1 * (1.0f / 512.0f), o1 + (size_t)(2 * i + 1) * 64);
    }
}

// ---------------------------------------------------------------------------
extern "C" void kernel_launch(void* const* d_in, const int* in_sizes, int n_in,
                              void* d_out, int out_size, void* d_ws, size_t ws_size,
                              hipStream_t stream) {
    const float* x_c = (const float*)d_in[0];
    const float* x_n = (const float*)d_in[1];
    const float* Wq  = (const float*)d_in[2];
    const float* bq  = (const float*)d_in[3];
    const float* Wk  = (const float*)d_in[4];
    const float* bk  = (const float*)d_in[5];
    float* out = (float*)d_out;

    char* ws = (char*)d_ws;
    unsigned short* Qbl = (unsigned short*)ws;                        // 4 MB
    unsigned short* Kbl = (unsigned short*)(ws + ((size_t)4 << 20));  // 4 MB

    proj_qk<<<dim3(NROWS / 64, 2), 256, 0, stream>>>(
        x_c, x_n, Wq, bq, Wk, bk, Qbl, Kbl);
    attn_fused<<<NROWS / 16, 512, 0, stream>>>(
        (const __bf16*)Qbl, (const __bf16*)Kbl, out);
}